// Round 1
// baseline (142.245 us; speedup 1.0000x reference)
//
#include <hip/hip_runtime.h>
#include <math.h>

// Problem constants (from reference): B,H,K,L,V = 4096,1024,10,64,80
constexpr int Bn = 4096;
constexpr int Hn = 1024;
constexpr int Kn = 10;
constexpr int Ln = 64;
constexpr int Vn = 80;
constexpr int NJ = 3 * Kn;   // 30
constexpr int R  = 4;        // batch rows per block
constexpr int NT = 256;

__global__ __launch_bounds__(NT) void window_kernel(
    const float* __restrict__ x,      // [B,H]
    const float* __restrict__ chars,  // [B,L,V]
    const float* __restrict__ W,      // [H,3K]
    const float* __restrict__ bias,   // [3K]
    float* __restrict__ out)          // [B,V]
{
    __shared__ float  xs[R * Hn];            // 16 KB, natural row layout
    __shared__ float  part[R * 256];         // 4 KB  (r, g*32+j)
    __shared__ float  abk[R * NJ];           // 480 B  exp(x@W+b)
    __shared__ float  phi_s[R * Ln];         // 1 KB
    __shared__ float4 cpart[R * 12 * 20];    // 15.36 KB

    const int t    = threadIdx.x;
    const int row0 = blockIdx.x * R;

    // ---- Stage x rows into LDS (coalesced float4, conflict-free) ----
    const float4* x4  = (const float4*)x;
    float4*       xs4 = (float4*)xs;
#pragma unroll
    for (int r = 0; r < R; ++r)
        xs4[r * (Hn / 4) + t] = x4[(size_t)(row0 + r) * (Hn / 4) + t];
    __syncthreads();

    // ---- GEMM partials: out[r][j] = sum_h x[r][h] * W[h][j] ----
    // thread: j = t&31 (j<30 active), g = t>>5 covers h in [128g, 128g+128)
    const int j = t & 31;
    const int g = t >> 5;
    float acc0 = 0.f, acc1 = 0.f, acc2 = 0.f, acc3 = 0.f;
    if (j < NJ) {
        const float* Wp = W + j;
        const int h0 = g * 128;
#pragma unroll 4
        for (int ii = 0; ii < 128; ii += 4) {
            const int h  = h0 + ii;
            const int h4 = h >> 2;
            float4 xa = xs4[0 * (Hn / 4) + h4];   // broadcast across j-lanes
            float4 xb = xs4[1 * (Hn / 4) + h4];
            float4 xc = xs4[2 * (Hn / 4) + h4];
            float4 xd = xs4[3 * (Hn / 4) + h4];
            float w0 = Wp[(h + 0) * NJ];
            float w1 = Wp[(h + 1) * NJ];
            float w2 = Wp[(h + 2) * NJ];
            float w3 = Wp[(h + 3) * NJ];
            acc0 += w0 * xa.x + w1 * xa.y + w2 * xa.z + w3 * xa.w;
            acc1 += w0 * xb.x + w1 * xb.y + w2 * xb.z + w3 * xb.w;
            acc2 += w0 * xc.x + w1 * xc.y + w2 * xc.z + w3 * xc.w;
            acc3 += w0 * xd.x + w1 * xd.y + w2 * xd.z + w3 * xd.w;
        }
    }
    part[0 * 256 + g * 32 + j] = acc0;
    part[1 * 256 + g * 32 + j] = acc1;
    part[2 * 256 + g * 32 + j] = acc2;
    part[3 * 256 + g * 32 + j] = acc3;
    __syncthreads();

    // ---- Reduce partials, add bias, exp -> alpha/beta/kappa (all are exp(raw)) ----
    if (t < R * NJ) {  // 120 threads
        const int r = t / NJ, jj = t % NJ;
        float s = bias[jj];
#pragma unroll
        for (int gg = 0; gg < 8; ++gg) s += part[r * 256 + gg * 32 + jj];
        abk[r * NJ + jj] = __expf(s);
    }
    __syncthreads();

    // ---- phi[r][l] = sum_k alpha * exp(-beta * (kappa - l)^2) ----
    {
        const int r = t >> 6, l = t & 63;
        const float lf = (float)l;
        const float* ab = abk + r * NJ;
        float ph = 0.f;
#pragma unroll
        for (int k = 0; k < Kn; ++k) {
            float a  = ab[k];
            float bt = ab[Kn + k];
            float kp = ab[2 * Kn + k];
            float d  = kp - lf;
            ph += a * __expf(-bt * d * d);
        }
        phi_s[r * Ln + l] = ph;
    }
    __syncthreads();

    // ---- window[r][v] = sum_l phi[r][l] * chars[r][l][v] ----
    const float4* c4 = (const float4*)chars;  // row stride = 64*80/4 = 1280 float4
    if (t < 240) {
        const int v4  = t % 20;   // float4 column
        const int g12 = t / 20;   // 12 l-groups
        float4 s0 = make_float4(0.f, 0.f, 0.f, 0.f);
        float4 s1 = s0, s2 = s0, s3 = s0;
        for (int l = g12; l < Ln; l += 12) {
            const int off = l * 20 + v4;
            float4 cA = c4[(size_t)(row0 + 0) * 1280 + off];
            float4 cB = c4[(size_t)(row0 + 1) * 1280 + off];
            float4 cC = c4[(size_t)(row0 + 2) * 1280 + off];
            float4 cD = c4[(size_t)(row0 + 3) * 1280 + off];
            float p0 = phi_s[0 * Ln + l];
            float p1 = phi_s[1 * Ln + l];
            float p2 = phi_s[2 * Ln + l];
            float p3 = phi_s[3 * Ln + l];
            s0.x += p0 * cA.x; s0.y += p0 * cA.y; s0.z += p0 * cA.z; s0.w += p0 * cA.w;
            s1.x += p1 * cB.x; s1.y += p1 * cB.y; s1.z += p1 * cB.z; s1.w += p1 * cB.w;
            s2.x += p2 * cC.x; s2.y += p2 * cC.y; s2.z += p2 * cC.z; s2.w += p2 * cC.w;
            s3.x += p3 * cD.x; s3.y += p3 * cD.y; s3.z += p3 * cD.z; s3.w += p3 * cD.w;
        }
        cpart[(0 * 12 + g12) * 20 + v4] = s0;
        cpart[(1 * 12 + g12) * 20 + v4] = s1;
        cpart[(2 * 12 + g12) * 20 + v4] = s2;
        cpart[(3 * 12 + g12) * 20 + v4] = s3;
    }
    __syncthreads();

    if (t < 80) {
        const int r  = t / 20;
        const int vv = t % 20;
        float4 s = make_float4(0.f, 0.f, 0.f, 0.f);
#pragma unroll
        for (int gg = 0; gg < 12; ++gg) {
            float4 p = cpart[(r * 12 + gg) * 20 + vv];
            s.x += p.x; s.y += p.y; s.z += p.z; s.w += p.w;
        }
        ((float4*)out)[(size_t)(row0 + r) * 20 + vv] = s;
    }
}

extern "C" void kernel_launch(void* const* d_in, const int* in_sizes, int n_in,
                              void* d_out, int out_size, void* d_ws, size_t ws_size,
                              hipStream_t stream) {
    const float* x     = (const float*)d_in[0];
    const float* chars = (const float*)d_in[1];
    const float* W     = (const float*)d_in[2];
    const float* bias  = (const float*)d_in[3];
    float* out = (float*)d_out;

    window_kernel<<<Bn / R, NT, 0, stream>>>(x, chars, W, bias, out);
}